// Round 1
// baseline (747.722 us; speedup 1.0000x reference)
//
#include <hip/hip_runtime.h>

#define S 2048
#define Dh 128
#define NB 16
#define OUT_ELEMS ((size_t)NB * S * Dh)   // 4194304 floats
#define NEG_BIG -1.0e9f
#define SCALE 0.08838834764831845f        // 1/sqrt(128)

typedef __attribute__((ext_vector_type(8))) short bf16x8;
typedef __attribute__((ext_vector_type(4))) float f32x4;
typedef __attribute__((ext_vector_type(4))) short s16x4;

__device__ __forceinline__ short f2bf(float x) {
    unsigned u = __float_as_uint(x);
    u += 0x7fffu + ((u >> 16) & 1u);      // RNE truncate to bf16 (no NaN inputs here)
    return (short)(u >> 16);
}

__device__ __forceinline__ s16x4 pack4(float4 v) {
    s16x4 r;
    r.x = f2bf(v.x); r.y = f2bf(v.y); r.z = f2bf(v.z); r.w = f2bf(v.w);
    return r;
}

// ---------------------------------------------------------------------------
// Mask dtype detection: int32-encoded bool has bytes 1..3 of each word == 0;
// u8-encoded random 0/1 mask has nonzero there with overwhelming probability.
// flag = 1 -> uint8 mask, flag = 0 -> int32 mask.
// ---------------------------------------------------------------------------
__global__ void detect_mask(const unsigned char* __restrict__ m, int* __restrict__ flag) {
    __shared__ int any;
    if (threadIdx.x == 0) any = 0;
    __syncthreads();
    int t = threadIdx.x;
    unsigned char v = (unsigned char)(m[t * 4 + 1] | m[t * 4 + 2] | m[t * 4 + 3]);
    if (v) atomicOr(&any, 1);
    __syncthreads();
    if (t == 0) *flag = any;
}

// ---------------------------------------------------------------------------
// V [b][k][n] fp32  ->  Vt [b][n][k] bf16 (k contiguous for MFMA B-fragments)
// grid: (32 k-blocks of 64, NB)
// ---------------------------------------------------------------------------
__global__ __launch_bounds__(256) void transpose_v(const float* __restrict__ V,
                                                   short* __restrict__ Vt) {
    const int kb = blockIdx.x, b = blockIdx.y;
    const float* Vb = V + ((size_t)b * S + kb * 64) * Dh;
    short* VtB = Vt + (size_t)b * Dh * S;
    __shared__ float Ls[64][132];
    const int t = threadIdx.x;
#pragma unroll
    for (int i = 0; i < 8; i++) {
        int idx = t + i * 256;
        int r = idx >> 5, c = (idx & 31) << 2;
        *(float4*)&Ls[r][c] = *(const float4*)(Vb + r * Dh + c);
    }
    __syncthreads();
#pragma unroll
    for (int i = 0; i < 8; i++) {
        int idx = t + i * 256;
        int n = idx >> 4, kc = (idx & 15) << 2;
        s16x4 o;
        o.x = f2bf(Ls[kc + 0][n]);
        o.y = f2bf(Ls[kc + 1][n]);
        o.z = f2bf(Ls[kc + 2][n]);
        o.w = f2bf(Ls[kc + 3][n]);
        *(s16x4*)(VtB + (size_t)n * S + kb * 64 + kc) = o;
    }
}

// ---------------------------------------------------------------------------
// Scores = (Q . K^T) * SCALE  (raw, pre-mask) written into attn region.
// gemm_bt pattern, mfma_f32_16x16x32_bf16, 128x128 tile, BK=64 (2 iters).
// grid: (16 kt, 16 qt, NB), block 256 (4 waves as 2x2 quadrants of 64x64).
// ---------------------------------------------------------------------------
__global__ __launch_bounds__(256, 2) void qk_kernel(const float* __restrict__ Q,
                                                    const float* __restrict__ Km,
                                                    float* __restrict__ Sc) {
    const int kt = blockIdx.x, qt = blockIdx.y, b = blockIdx.z;
    const float* Qb = Q + ((size_t)b * S + qt * 128) * Dh;
    const float* Kb = Km + ((size_t)b * S + kt * 128) * Dh;
    __shared__ short As[128][72];
    __shared__ short Bs[128][72];
    const int t = threadIdx.x;
    const int w = t >> 6, lane = t & 63, fr = lane & 15, quad = lane >> 4;
    const int mw = (w >> 1) * 64, nw = (w & 1) * 64;
    f32x4 acc[4][4] = {};

    for (int k0 = 0; k0 < Dh; k0 += 64) {
        __syncthreads();
#pragma unroll
        for (int i = 0; i < 8; i++) {
            int idx = t + i * 256;
            int r = idx >> 4, c = (idx & 15) << 2;   // 16 float4 per 64-col row
            float4 qv = *(const float4*)(Qb + r * Dh + k0 + c);
            float4 kv = *(const float4*)(Kb + r * Dh + k0 + c);
            *(s16x4*)&As[r][c] = pack4(qv);
            *(s16x4*)&Bs[r][c] = pack4(kv);
        }
        __syncthreads();
#pragma unroll
        for (int kc = 0; kc < 2; kc++) {
            const int ko = kc * 32 + quad * 8;
            bf16x8 af[4], bf[4];
#pragma unroll
            for (int mi = 0; mi < 4; mi++) af[mi] = *(const bf16x8*)&As[mw + mi * 16 + fr][ko];
#pragma unroll
            for (int ni = 0; ni < 4; ni++) bf[ni] = *(const bf16x8*)&Bs[nw + ni * 16 + fr][ko];
#pragma unroll
            for (int mi = 0; mi < 4; mi++)
#pragma unroll
                for (int ni = 0; ni < 4; ni++)
                    acc[mi][ni] = __builtin_amdgcn_mfma_f32_16x16x32_bf16(af[mi], bf[ni], acc[mi][ni], 0, 0, 0);
        }
    }

    float* ScB = Sc + (size_t)b * S * S;
#pragma unroll
    for (int mi = 0; mi < 4; mi++)
#pragma unroll
        for (int ni = 0; ni < 4; ni++)
#pragma unroll
            for (int r = 0; r < 4; r++) {
                int row = qt * 128 + mw + mi * 16 + quad * 4 + r;   // C: row = quad*4+reg
                int col = kt * 128 + nw + ni * 16 + fr;             // C: col = lane&15
                ScB[(size_t)row * S + col] = acc[mi][ni][r] * SCALE;
            }
}

// ---------------------------------------------------------------------------
// Row-wise mask + softmax, in place on the attn region.
// One wave per row (4 rows / block), 32 scores per lane in registers.
// grid: (512, NB), block 256.
// ---------------------------------------------------------------------------
__global__ __launch_bounds__(256) void softmax_kernel(float* __restrict__ Sc,
                                                      const void* __restrict__ maskp,
                                                      const int* __restrict__ flagp) {
    const int b = blockIdx.y;
    const int w = threadIdx.x >> 6, lane = threadIdx.x & 63;
    const int row = blockIdx.x * 4 + w;
    float* R = Sc + ((size_t)b * S + row) * S;
    float4* R4 = (float4*)R;
    const int flag = flagp ? *flagp : 0;

    float sv[32];
    if (flag) {
        const uchar4* M4 = (const uchar4*)((const unsigned char*)maskp + ((size_t)b * S + row) * S);
#pragma unroll
        for (int j = 0; j < 8; j++) {
            float4 v = R4[lane + 64 * j];
            uchar4 m = M4[lane + 64 * j];
            sv[4 * j + 0] = m.x ? NEG_BIG : v.x;
            sv[4 * j + 1] = m.y ? NEG_BIG : v.y;
            sv[4 * j + 2] = m.z ? NEG_BIG : v.z;
            sv[4 * j + 3] = m.w ? NEG_BIG : v.w;
        }
    } else {
        const int4* M4 = (const int4*)((const int*)maskp + ((size_t)b * S + row) * S);
#pragma unroll
        for (int j = 0; j < 8; j++) {
            float4 v = R4[lane + 64 * j];
            int4 m = M4[lane + 64 * j];
            sv[4 * j + 0] = m.x ? NEG_BIG : v.x;
            sv[4 * j + 1] = m.y ? NEG_BIG : v.y;
            sv[4 * j + 2] = m.z ? NEG_BIG : v.z;
            sv[4 * j + 3] = m.w ? NEG_BIG : v.w;
        }
    }

    float mx = sv[0];
#pragma unroll
    for (int i = 1; i < 32; i++) mx = fmaxf(mx, sv[i]);
    for (int o = 32; o > 0; o >>= 1) mx = fmaxf(mx, __shfl_xor(mx, o, 64));

    float sum = 0.f;
#pragma unroll
    for (int i = 0; i < 32; i++) {
        sv[i] = __expf(sv[i] - mx);
        sum += sv[i];
    }
    for (int o = 32; o > 0; o >>= 1) sum += __shfl_xor(sum, o, 64);
    const float inv = 1.0f / sum;

#pragma unroll
    for (int j = 0; j < 8; j++) {
        float4 p;
        p.x = sv[4 * j + 0] * inv;
        p.y = sv[4 * j + 1] * inv;
        p.z = sv[4 * j + 2] * inv;
        p.w = sv[4 * j + 3] * inv;
        R4[lane + 64 * j] = p;
    }
}

// ---------------------------------------------------------------------------
// out = attn . V.  64-row M-tiles (grid 32 x NB = 512 blocks, 2/CU).
// A (attn fp32) staged via LDS -> bf16; B from pre-transposed Vt (bf16,
// k-contiguous, L1/L2-hot) or strided fallback gather from V.
// ---------------------------------------------------------------------------
__global__ __launch_bounds__(256, 2) void pv_kernel(const float* __restrict__ Sc,
                                                    const float* __restrict__ V,
                                                    const short* __restrict__ Vt,
                                                    const int useVt,
                                                    float* __restrict__ Out) {
    const int mt = blockIdx.x, b = blockIdx.y;
    const float* ScB = Sc + (size_t)b * S * S + (size_t)mt * 64 * S;
    const float* Vb = V + (size_t)b * S * Dh;
    const short* VtB = Vt + (size_t)b * Dh * S;
    float* OutB = Out + ((size_t)b * S + mt * 64) * Dh;
    __shared__ short As[64][72];
    const int t = threadIdx.x, w = t >> 6, lane = t & 63, fr = lane & 15, quad = lane >> 4;
    const int mw = (w >> 1) * 32, nw = (w & 1) * 64;
    f32x4 acc[2][4] = {};

    for (int k0 = 0; k0 < S; k0 += 64) {
        __syncthreads();
#pragma unroll
        for (int i = 0; i < 4; i++) {
            int idx = t + i * 256;
            int r = idx >> 4, c = (idx & 15) << 2;
            float4 v = *(const float4*)(ScB + (size_t)r * S + k0 + c);
            *(s16x4*)&As[r][c] = pack4(v);
        }
        __syncthreads();
#pragma unroll
        for (int kc = 0; kc < 2; kc++) {
            const int ko = kc * 32 + quad * 8;
            bf16x8 af[2], bf[4];
#pragma unroll
            for (int mi = 0; mi < 2; mi++) af[mi] = *(const bf16x8*)&As[mw + mi * 16 + fr][ko];
            if (useVt) {
#pragma unroll
                for (int ni = 0; ni < 4; ni++)
                    bf[ni] = *(const bf16x8*)(VtB + (size_t)(nw + ni * 16 + fr) * S + k0 + ko);
            } else {
#pragma unroll
                for (int ni = 0; ni < 4; ni++) {
                    int n = nw + ni * 16 + fr;
#pragma unroll
                    for (int j = 0; j < 8; j++) bf[ni][j] = f2bf(Vb[(size_t)(k0 + ko + j) * Dh + n]);
                }
            }
#pragma unroll
            for (int mi = 0; mi < 2; mi++)
#pragma unroll
                for (int ni = 0; ni < 4; ni++)
                    acc[mi][ni] = __builtin_amdgcn_mfma_f32_16x16x32_bf16(af[mi], bf[ni], acc[mi][ni], 0, 0, 0);
        }
    }

#pragma unroll
    for (int mi = 0; mi < 2; mi++)
#pragma unroll
        for (int ni = 0; ni < 4; ni++)
#pragma unroll
            for (int r = 0; r < 4; r++) {
                int row = mw + mi * 16 + quad * 4 + r;
                int col = nw + ni * 16 + fr;
                OutB[(size_t)row * Dh + col] = acc[mi][ni][r];
            }
}

extern "C" void kernel_launch(void* const* d_in, const int* in_sizes, int n_in,
                              void* d_out, int out_size, void* d_ws, size_t ws_size,
                              hipStream_t stream) {
    const float* Q = (const float*)d_in[0];
    const float* Km = (const float*)d_in[1];
    const float* V = (const float*)d_in[2];
    const void* M = d_in[3];
    float* out = (float*)d_out;
    float* attn = out + OUT_ELEMS;

    const size_t VT_BYTES = (size_t)NB * Dh * S * sizeof(short);  // 8 MB
    const int useVt = (ws_size >= VT_BYTES + 64) ? 1 : 0;
    int* flag = nullptr;
    if (ws_size >= (size_t)(useVt ? VT_BYTES + 64 : 64))
        flag = (int*)((char*)d_ws + (useVt ? VT_BYTES : 0));

    if (flag) detect_mask<<<1, 256, 0, stream>>>((const unsigned char*)M, flag);
    if (useVt) transpose_v<<<dim3(32, NB), 256, 0, stream>>>(V, (short*)d_ws);
    qk_kernel<<<dim3(16, 16, NB), 256, 0, stream>>>(Q, Km, attn);
    softmax_kernel<<<dim3(512, NB), 256, 0, stream>>>(attn, M, flag);
    pv_kernel<<<dim3(32, NB), 256, 0, stream>>>(attn, V, (const short*)d_ws, useVt, out);
}